// Round 1
// baseline (204.345 us; speedup 1.0000x reference)
//
#include <hip/hip_runtime.h>
#include <math.h>

#define NPTS 8192
#define TPR 8            // threads per row
#define RPB 32           // rows per block
#define BLOCK 256
#define TILE 1024
#define NTILE (NPTS/TILE)
#define K9 9

// acc layout: acc[0]=align_sum acc[1]=align_cnt acc[2]=flat_sum acc[3]=dens_sum
__global__ __launch_bounds__(BLOCK) void gsr_main(
    const float* __restrict__ pos,   // N*3
    const float* __restrict__ rot,   // N*4
    const float* __restrict__ scl,   // N*3
    const float* __restrict__ opa,   // N
    float* __restrict__ acc)
{
    __shared__ float4 ps[TILE];                // (x,y,z,|p|^2)
    __shared__ float4 rs[TILE];                // rotation
    __shared__ float  mbuf[RPB*TPR*K9];        // per-row partial top-9 lists
    __shared__ float  red[4][4];               // wave partials x 4 quantities

    const int tid = threadIdx.x;
    const int row_local = tid / TPR;
    const int t8 = tid % TPR;
    const int i = blockIdx.x * RPB + row_local;

    const float xi = pos[3*i], yi = pos[3*i+1], zi = pos[3*i+2];
    const float sqi = xi*xi + yi*yi + zi*zi;
    const float4 q = *(const float4*)(rot + 4*i);

    float d[K9];
    #pragma unroll
    for (int k = 0; k < K9; k++) d[k] = 1e30f;
    float asum = 0.f, acnt = 0.f;

    for (int t = 0; t < NTILE; t++) {
        __syncthreads();
        for (int e = tid; e < TILE; e += BLOCK) {
            int j = t*TILE + e;
            float xj = pos[3*j], yj = pos[3*j+1], zj = pos[3*j+2];
            ps[e] = make_float4(xj, yj, zj, xj*xj + yj*yj + zj*zj);
            rs[e] = *(const float4*)(rot + 4*j);
        }
        __syncthreads();
        const int jbase = t*TILE;
        for (int it = 0; it < TILE/TPR; it++) {
            int e = it*TPR + t8;
            float4 pj = ps[e];
            float dot3 = xi*pj.x + yi*pj.y + zi*pj.z;
            float d2 = sqi + pj.w - 2.f*dot3;
            int j = jbase + e;
            bool self = (j == i);
            if (self) d2 = 0.f;                 // exact diagonal, matches ref
            float d2p = fmaxf(d2, 0.f) + 1e-12f; // monotone proxy for dist
            // branch-free sorted insertion, d[] ascending, keeps 9 smallest
            float v = d2p;
            #pragma unroll
            for (int k = 0; k < K9; k++) {
                float lo = fminf(d[k], v);
                v = fmaxf(d[k], v);
                d[k] = lo;
            }
            if (d2p < 4e-4f && !self) {          // dist < 0.02
                float4 rj = rs[e];
                float dq = q.x*rj.x + q.y*rj.y + q.z*rj.z + q.w*rj.w;
                asum += 1.f - fabsf(dq);
                acnt += 1.f;
            }
        }
    }

    __syncthreads();
    #pragma unroll
    for (int k = 0; k < K9; k++) mbuf[(row_local*TPR + t8)*K9 + k] = d[k];
    __syncthreads();

    float flat = 0.f, dens = 0.f;
    if (t8 == 0) {
        // merge the row's 8 partial lists (72 values) -> global top-9
        float md[K9];
        #pragma unroll
        for (int k = 0; k < K9; k++) md[k] = 1e30f;
        const float* mb = &mbuf[row_local*TPR*K9];
        for (int m = 0; m < TPR*K9; m++) {
            float v = mb[m];
            #pragma unroll
            for (int k = 0; k < K9; k++) {
                float lo = fminf(md[k], v);
                v = fmaxf(md[k], v);
                md[k] = lo;
            }
        }
        float s = 0.f;
        #pragma unroll
        for (int k = 1; k < K9; k++) s += sqrtf(md[k]);  // drop self (md[0])
        float avg = s * 0.125f;
        dens = fabsf(avg - 0.01f) * opa[i];
        // flatness (per-row, do it once here)
        float a = expf(scl[3*i]), b = expf(scl[3*i+1]), c = expf(scl[3*i+2]);
        float mn  = fminf(a, fminf(b, c));
        float mx  = fmaxf(a, fmaxf(b, c));
        float mid = fminf(fmaxf(a, b), fmaxf(fminf(a, b), c));  // exact median
        float fr  = logf(mx / (mn + 1e-8f) + 1e-8f);
        float dsim = 1.f / (fabsf(mx - mid) + 0.001f);
        flat = fr + 0.1f * dsim;
    }

    // block-reduce 4 scalars
    float vals[4] = {asum, acnt, flat, dens};
    const int lane = tid & 63;
    const int wave = tid >> 6;
    #pragma unroll
    for (int qi = 0; qi < 4; qi++) {
        float v = vals[qi];
        for (int o = 32; o > 0; o >>= 1) v += __shfl_down(v, o, 64);
        if (lane == 0) red[wave][qi] = v;
    }
    __syncthreads();
    if (tid == 0) {
        float t0 = 0, t1 = 0, t2 = 0, t3 = 0;
        for (int w = 0; w < 4; w++) {
            t0 += red[w][0]; t1 += red[w][1]; t2 += red[w][2]; t3 += red[w][3];
        }
        atomicAdd(&acc[0], t0);
        atomicAdd(&acc[1], t1);
        atomicAdd(&acc[2], t2);
        atomicAdd(&acc[3], t3);
    }
}

__global__ void gsr_final(const float* __restrict__ acc, float* __restrict__ out)
{
    float flat_loss = -acc[2] / (float)NPTS;
    float align_loss = (acc[1] > 0.f) ? (acc[0] / acc[1]) : 0.f;
    float dens_loss = acc[3] / (float)NPTS;
    out[0] = 1.0f * flat_loss + 0.5f * align_loss + 0.2f * dens_loss;
}

extern "C" void kernel_launch(void* const* d_in, const int* in_sizes, int n_in,
                              void* d_out, int out_size, void* d_ws, size_t ws_size,
                              hipStream_t stream) {
    const float* pos = (const float*)d_in[0];
    const float* rot = (const float*)d_in[1];
    const float* scl = (const float*)d_in[2];
    const float* opa = (const float*)d_in[3];
    float* acc = (float*)d_ws;

    hipMemsetAsync(acc, 0, 4 * sizeof(float), stream);
    gsr_main<<<dim3(NPTS/RPB), dim3(BLOCK), 0, stream>>>(pos, rot, scl, opa, acc);
    gsr_final<<<1, 1, 0, stream>>>(acc, (float*)d_out);
}

// Round 2
// 152.665 us; speedup vs baseline: 1.3385x; 1.3385x over previous
//
#include <hip/hip_runtime.h>
#include <math.h>

#define NPTS 8192
#define TPR 32           // threads per row
#define RPB 32           // rows per block
#define BLOCK 1024       // RPB * TPR
#define TILE 1024
#define NTILE (NPTS/TILE)
#define K9 9
#define NWAVE (BLOCK/64)

// acc layout: acc[0]=align_sum acc[1]=align_cnt acc[2]=flat_sum acc[3]=dens_sum
__global__ __launch_bounds__(BLOCK) void gsr_main(
    const float* __restrict__ pos,   // N*3
    const float* __restrict__ rot,   // N*4
    const float* __restrict__ scl,   // N*3
    const float* __restrict__ opa,   // N
    float* __restrict__ acc)
{
    __shared__ float4 ps[TILE];                // (x,y,z,|p|^2)  16 KB
    __shared__ float4 rs[TILE];                // rotation       16 KB
    __shared__ float  mbuf[RPB*TPR*K9];        // partial top-9 lists, 36 KB
    __shared__ float  red[NWAVE][4];           // wave partials

    const int tid = threadIdx.x;
    const int row_local = tid / TPR;           // 0..31
    const int t32 = tid % TPR;                 // 0..31
    const int i = blockIdx.x * RPB + row_local;

    const float xi = pos[3*i], yi = pos[3*i+1], zi = pos[3*i+2];
    const float sqi = xi*xi + yi*yi + zi*zi;
    const float4 q = *(const float4*)(rot + 4*i);

    float da[K9], db[K9];
    #pragma unroll
    for (int k = 0; k < K9; k++) { da[k] = 1e30f; db[k] = 1e30f; }
    float asum = 0.f, acnt = 0.f;

    for (int t = 0; t < NTILE; t++) {
        __syncthreads();
        {
            int j = t*TILE + tid;               // BLOCK == TILE: one elem/thread
            float xj = pos[3*j], yj = pos[3*j+1], zj = pos[3*j+2];
            ps[tid] = make_float4(xj, yj, zj, xj*xj + yj*yj + zj*zj);
            rs[tid] = *(const float4*)(rot + 4*j);
        }
        __syncthreads();
        const int jbase = t*TILE;
        #pragma unroll 2
        for (int it = 0; it < TILE/(2*TPR); it++) {   // 16 dual iterations
            int e0 = (2*it)*TPR + t32;
            int e1 = e0 + TPR;
            float4 p0 = ps[e0];
            float4 p1 = ps[e1];
            float dot0 = fmaf(xi, p0.x, fmaf(yi, p0.y, zi*p0.z));
            float dot1 = fmaf(xi, p1.x, fmaf(yi, p1.y, zi*p1.z));
            float c0 = fmaxf(fmaf(-2.f, dot0, sqi + p0.w), 0.f);
            float c1 = fmaxf(fmaf(-2.f, dot1, sqi + p1.w), 0.f);
            // two independent branch-free sorted insertions (ascending)
            float v0 = c0, v1 = c1;
            #pragma unroll
            for (int k = 0; k < K9; k++) {
                float lo0 = fminf(da[k], v0);
                float lo1 = fminf(db[k], v1);
                v0 = fmaxf(da[k], v0);
                v1 = fmaxf(db[k], v1);
                da[k] = lo0;
                db[k] = lo1;
            }
            // rare alignment accumulation (dist < 0.02  <=>  c < 4e-4)
            if (c0 < 4e-4f) {
                int j = jbase + e0;
                if (j != i) {
                    float4 rj = rs[e0];
                    float dq = fmaf(q.x, rj.x, fmaf(q.y, rj.y, fmaf(q.z, rj.z, q.w*rj.w)));
                    asum += 1.f - fabsf(dq);
                    acnt += 1.f;
                }
            }
            if (c1 < 4e-4f) {
                int j = jbase + e1;
                if (j != i) {
                    float4 rj = rs[e1];
                    float dq = fmaf(q.x, rj.x, fmaf(q.y, rj.y, fmaf(q.z, rj.z, q.w*rj.w)));
                    asum += 1.f - fabsf(dq);
                    acnt += 1.f;
                }
            }
        }
    }

    // merge db into da (81 min/max, once)
    #pragma unroll
    for (int m = 0; m < K9; m++) {
        float v = db[m];
        #pragma unroll
        for (int k = 0; k < K9; k++) {
            float lo = fminf(da[k], v);
            v = fmaxf(da[k], v);
            da[k] = lo;
        }
    }

    __syncthreads();
    #pragma unroll
    for (int k = 0; k < K9; k++) mbuf[(row_local*TPR + t32)*K9 + k] = da[k];
    __syncthreads();

    // stage 1: 4 threads/row each merge 8 lists -> write into first list of own group
    if (t32 < 4) {
        float md[K9];
        #pragma unroll
        for (int k = 0; k < K9; k++) md[k] = 1e30f;
        const float* mb = &mbuf[(row_local*TPR + t32*8)*K9];
        for (int m = 0; m < 8*K9; m++) {
            float v = mb[m];
            #pragma unroll
            for (int k = 0; k < K9; k++) {
                float lo = fminf(md[k], v);
                v = fmaxf(md[k], v);
                md[k] = lo;
            }
        }
        float* out = &mbuf[(row_local*TPR + t32*8)*K9];
        #pragma unroll
        for (int k = 0; k < K9; k++) out[k] = md[k];
    }
    __syncthreads();

    float flat = 0.f, dens = 0.f;
    if (t32 == 0) {
        // stage 2: merge the 4 stage-1 lists
        float md[K9];
        #pragma unroll
        for (int k = 0; k < K9; k++) md[k] = 1e30f;
        #pragma unroll
        for (int g = 0; g < 4; g++) {
            const float* mb = &mbuf[(row_local*TPR + g*8)*K9];
            for (int m = 0; m < K9; m++) {
                float v = mb[m];
                #pragma unroll
                for (int k = 0; k < K9; k++) {
                    float lo = fminf(md[k], v);
                    v = fmaxf(md[k], v);
                    md[k] = lo;
                }
            }
        }
        float s = 0.f;
        #pragma unroll
        for (int k = 1; k < K9; k++) s += sqrtf(md[k] + 1e-12f);  // drop self
        float avg = s * 0.125f;
        dens = fabsf(avg - 0.01f) * opa[i];
        // flatness (per-row)
        float a = expf(scl[3*i]), b = expf(scl[3*i+1]), c = expf(scl[3*i+2]);
        float mn  = fminf(a, fminf(b, c));
        float mx  = fmaxf(a, fmaxf(b, c));
        float mid = fminf(fmaxf(a, b), fmaxf(fminf(a, b), c));
        float fr  = logf(mx / (mn + 1e-8f) + 1e-8f);
        float dsim = 1.f / (fabsf(mx - mid) + 0.001f);
        flat = fr + 0.1f * dsim;
    }

    // block-reduce 4 scalars
    float vals[4] = {asum, acnt, flat, dens};
    const int lane = tid & 63;
    const int wave = tid >> 6;
    #pragma unroll
    for (int qi = 0; qi < 4; qi++) {
        float v = vals[qi];
        for (int o = 32; o > 0; o >>= 1) v += __shfl_down(v, o, 64);
        if (lane == 0) red[wave][qi] = v;
    }
    __syncthreads();
    if (tid == 0) {
        float t0 = 0, t1 = 0, t2 = 0, t3 = 0;
        for (int w = 0; w < NWAVE; w++) {
            t0 += red[w][0]; t1 += red[w][1]; t2 += red[w][2]; t3 += red[w][3];
        }
        atomicAdd(&acc[0], t0);
        atomicAdd(&acc[1], t1);
        atomicAdd(&acc[2], t2);
        atomicAdd(&acc[3], t3);
    }
}

__global__ void gsr_final(const float* __restrict__ acc, float* __restrict__ out)
{
    float flat_loss = -acc[2] / (float)NPTS;
    float align_loss = (acc[1] > 0.f) ? (acc[0] / acc[1]) : 0.f;
    float dens_loss = acc[3] / (float)NPTS;
    out[0] = 1.0f * flat_loss + 0.5f * align_loss + 0.2f * dens_loss;
}

extern "C" void kernel_launch(void* const* d_in, const int* in_sizes, int n_in,
                              void* d_out, int out_size, void* d_ws, size_t ws_size,
                              hipStream_t stream) {
    const float* pos = (const float*)d_in[0];
    const float* rot = (const float*)d_in[1];
    const float* scl = (const float*)d_in[2];
    const float* opa = (const float*)d_in[3];
    float* acc = (float*)d_ws;

    hipMemsetAsync(acc, 0, 4 * sizeof(float), stream);
    gsr_main<<<dim3(NPTS/RPB), dim3(BLOCK), 0, stream>>>(pos, rot, scl, opa, acc);
    gsr_final<<<1, 1, 0, stream>>>(acc, (float*)d_out);
}